// Round 16
// baseline (365.510 us; speedup 1.0000x reference)
//
#include <hip/hip_runtime.h>
#include <math.h>

#define N_ROWS 100000
#define NG     2000
#define M0     256
#define M1     128
#define DIMX   640
#define EPSV   1e-5f
#define BM     32

#define INV_SQRT3 0.57735026918962576f
#define INV_SQRT2 0.70710678118654752f

#define OFF_U  0
#define OFF_D  98304
#define OFF_V  131072
#define WT_TOTAL 163840

typedef __attribute__((ext_vector_type(8))) short bf16x8;
typedef __attribute__((ext_vector_type(4))) float f32x4;

__device__ __forceinline__ unsigned short f2bf(float f) {
    union { float f; unsigned int u; } v; v.f = f;
    unsigned int r = v.u + 0x7fff + ((v.u >> 16) & 1);
    return (unsigned short)(r >> 16);
}
__device__ __forceinline__ float bf2f(unsigned short u) {
    union { unsigned int u; float f; } v; v.u = ((unsigned int)u) << 16; return v.f;
}
__device__ __forceinline__ float2 bf2x2(unsigned int w) {
    return make_float2(bf2f((unsigned short)(w & 0xffffu)),
                       bf2f((unsigned short)(w >> 16)));
}

__device__ __forceinline__ int lower_bound_i(const int* __restrict__ b, int n, int key) {
    int lo = 0, hi = n;
    while (lo < hi) { int m = (lo + hi) >> 1; if (b[m] < key) lo = m + 1; else hi = m; }
    return lo;
}

// ---------------------------------------------------------------------------
// k0: pack weights -> bf16 per-MFMA-tile layout, scales folded. (R15 verbatim)
// ---------------------------------------------------------------------------
__global__ __launch_bounds__(256)
void k0_pack(const float* __restrict__ w000, const float* __restrict__ w011,
             const float* __restrict__ w101, const float* __restrict__ w110,
             const float* __restrict__ w111, unsigned short* __restrict__ WT)
{
    int i = blockIdx.x * 256 + threadIdx.x;
    if (i >= WT_TOTAL) return;
    int l = (i >> 3) & 63, e = i & 7;
    int lc = l & 15, lk = (l >> 4) << 3;
    float val;
    if (i < OFF_D) {
        int tile = i >> 9; int f = tile >> 3, kk = tile & 7;
        int col = f * 16 + lc, k = kk * 32 + lk + e;
        val = (col < 256) ? w000[k * 256 + col] : w011[k * 128 + (col - 256)];
    } else if (i < OFF_V) {
        int j = i - OFF_D; int tile = j >> 9; int f = tile >> 2, kk = tile & 3;
        int col = f * 16 + lc, k = kk * 32 + lk + e;
        val = w110[k * 256 + col] * INV_SQRT3;
    } else {
        int j = i - OFF_V; int tile = j >> 9; int f = tile >> 2, kk = tile & 3;
        int col = f * 16 + lc, k = kk * 32 + lk + e;
        val = (col < 128) ? w101[k * 128 + col]
                          : w111[k * 128 + (col - 128)] * INV_SQRT2;
    }
    WT[i] = f2bf(val);
}

__device__ __forceinline__ bf16x8 ldA(const unsigned short* base, int KW,
                                      int row, int kk, int kg)
{
    int off = row * KW + (((kk << 5) + (kg << 3)) ^ ((row & 7) << 3));
    return *(const bf16x8*)(base + off);
}

// ---------------------------------------------------------------------------
// k1: R15 verbatim (proven 181 us; bf16 scratch stores).
// ---------------------------------------------------------------------------
__global__ __launch_bounds__(256, 3)
void k1_mfma(const float* __restrict__ x, const float* __restrict__ y,
             const unsigned short* __restrict__ WT, const float* __restrict__ bias0,
             unsigned short* __restrict__ scr)
{
    __shared__ unsigned short xs1[BM][256];
    __shared__ unsigned short xv[3][BM][128];
    __shared__ unsigned short xd[BM][128];
    __shared__ float sY[BM][4];
    __shared__ float sBias[256];

    const int t    = threadIdx.x;
    const int lane = t & 63;
    const int wv   = t >> 6;
    const int cb   = lane & 15;
    const int kg   = lane >> 4;
    const int hy   = blockIdx.x & 1;
    const int n0   = (blockIdx.x >> 1) * BM;

    if (t < 128) sY[t >> 2][t & 3] = y[(size_t)(n0 + (t >> 2)) * 4 + (t & 3)];
    sBias[t] = bias0[t];

    // ---- stage x once: s1 and deinterleaved v1 ----
    #pragma unroll
    for (int i = 0; i < 8; ++i) {
        int idx = i * 256 + t;
        int r = idx >> 6, c4 = idx & 63;
        float4 v = *(const float4*)(x + (size_t)(n0 + r) * DIMX + c4 * 4);
        ushort4 o = { f2bf(v.x), f2bf(v.y), f2bf(v.z), f2bf(v.w) };
        *(ushort4*)&xs1[r][(c4 * 4) ^ ((r & 7) << 3)] = o;
    }
    #pragma unroll
    for (int i = 0; i < 4; ++i) {
        int idx = i * 256 + t;
        int r = idx >> 5, q = idx & 31;
        const float* vp = x + (size_t)(n0 + r) * DIMX + M0 + q * 12;
        float4 a = *(const float4*)vp;
        float4 b = *(const float4*)(vp + 4);
        float4 c = *(const float4*)(vp + 8);
        int off = (q * 4) ^ ((r & 7) << 3);
        ushort4 ox = { f2bf(a.x), f2bf(a.w), f2bf(b.z), f2bf(c.y) };
        ushort4 oy = { f2bf(a.y), f2bf(b.x), f2bf(b.w), f2bf(c.z) };
        ushort4 oz = { f2bf(a.z), f2bf(b.y), f2bf(c.x), f2bf(c.w) };
        *(ushort4*)&xv[0][r][off] = ox;
        *(ushort4*)&xv[1][r][off] = oy;
        *(ushort4*)&xv[2][r][off] = oz;
    }
    __syncthreads();

    // ---- d = v1 . v2 ----
    #pragma unroll
    for (int i = 0; i < 4; ++i) {
        int idx = i * 256 + t;
        int r = idx >> 5, q = idx & 31;
        int off = (q * 4) ^ ((r & 7) << 3);
        ushort4 ux = *(const ushort4*)&xv[0][r][off];
        ushort4 uy = *(const ushort4*)&xv[1][r][off];
        ushort4 uz = *(const ushort4*)&xv[2][r][off];
        float v2x = sY[r][1], v2y = sY[r][2], v2z = sY[r][3];
        ushort4 od;
        od.x = f2bf(bf2f(ux.x) * v2x + bf2f(uy.x) * v2y + bf2f(uz.x) * v2z);
        od.y = f2bf(bf2f(ux.y) * v2x + bf2f(uy.y) * v2y + bf2f(uz.y) * v2z);
        od.z = f2bf(bf2f(ux.z) * v2x + bf2f(uy.z) * v2y + bf2f(uz.z) * v2z);
        od.w = f2bf(bf2f(ux.w) * v2x + bf2f(uy.w) * v2y + bf2f(uz.w) * v2z);
        *(ushort4*)&xd[r][off] = od;
    }
    __syncthreads();

    float s2v[2][4];
    #pragma unroll
    for (int rg = 0; rg < 2; ++rg)
        #pragma unroll
        for (int j = 0; j < 4; ++j)
            s2v[rg][j] = sY[rg * 16 + kg * 4 + j][0];

    // ---- U phase: [out0_raw | G2] = s1 @ [W000 | W011], K=256 ----
    f32x4 aO[2][2];
    f32x4 aG[2];
    #pragma unroll
    for (int q = 0; q < 2; ++q) { aO[q][0] = (f32x4){0,0,0,0}; aO[q][1] = (f32x4){0,0,0,0}; }
    aG[0] = (f32x4){0,0,0,0}; aG[1] = (f32x4){0,0,0,0};

    #pragma unroll
    for (int kk = 0; kk < 8; ++kk) {
        bf16x8 a0 = ldA(&xs1[0][0], 256, cb, kk, kg);
        bf16x8 a1 = ldA(&xs1[0][0], 256, 16 + cb, kk, kg);
        #pragma unroll
        for (int q = 0; q < 3; ++q) {
            int f = (q < 2) ? (wv * 4 + hy * 2 + q) : (16 + wv * 2 + hy);
            bf16x8 b = *(const bf16x8*)(WT + OFF_U + (size_t)(f * 8 + kk) * 512 + lane * 8);
            if (q < 2) {
                aO[q][0] = __builtin_amdgcn_mfma_f32_16x16x32_bf16(a0, b, aO[q][0], 0, 0, 0);
                aO[q][1] = __builtin_amdgcn_mfma_f32_16x16x32_bf16(a1, b, aO[q][1], 0, 0, 0);
            } else {
                aG[0] = __builtin_amdgcn_mfma_f32_16x16x32_bf16(a0, b, aG[0], 0, 0, 0);
                aG[1] = __builtin_amdgcn_mfma_f32_16x16x32_bf16(a1, b, aG[1], 0, 0, 0);
            }
        }
    }

    #pragma unroll
    for (int q = 0; q < 2; ++q)
        #pragma unroll
        for (int rg = 0; rg < 2; ++rg)
            #pragma unroll
            for (int j = 0; j < 4; ++j)
                aO[q][rg][j] *= s2v[rg][j];

    #pragma unroll
    for (int kk = 0; kk < 4; ++kk) {
        bf16x8 a0 = ldA(&xd[0][0], 128, cb, kk, kg);
        bf16x8 a1 = ldA(&xd[0][0], 128, 16 + cb, kk, kg);
        #pragma unroll
        for (int q = 0; q < 2; ++q) {
            int f = wv * 4 + hy * 2 + q;
            bf16x8 b = *(const bf16x8*)(WT + OFF_D + (size_t)(f * 4 + kk) * 512 + lane * 8);
            aO[q][0] = __builtin_amdgcn_mfma_f32_16x16x32_bf16(a0, b, aO[q][0], 0, 0, 0);
            aO[q][1] = __builtin_amdgcn_mfma_f32_16x16x32_bf16(a1, b, aO[q][1], 0, 0, 0);
        }
    }

    // out0 epilogue -> bf16 scratch
    #pragma unroll
    for (int q = 0; q < 2; ++q) {
        int col = wv * 64 + hy * 32 + q * 16 + cb;
        float bb = sBias[col];
        #pragma unroll
        for (int rg = 0; rg < 2; ++rg)
            #pragma unroll
            for (int j = 0; j < 4; ++j) {
                int row = rg * 16 + kg * 4 + j;
                scr[(size_t)(n0 + row) * DIMX + col] = f2bf(aO[q][rg][j] + bb);
            }
    }

    // ---- V phase ----
    f32x4 aV[2][3][2];
    #pragma unroll
    for (int q = 0; q < 2; ++q)
        #pragma unroll
        for (int j = 0; j < 3; ++j) { aV[q][j][0] = (f32x4){0,0,0,0}; aV[q][j][1] = (f32x4){0,0,0,0}; }

    #pragma unroll
    for (int kk = 0; kk < 4; ++kk) {
        bf16x8 av[3][2];
        #pragma unroll
        for (int j = 0; j < 3; ++j) {
            av[j][0] = ldA(&xv[j][0][0], 128, cb, kk, kg);
            av[j][1] = ldA(&xv[j][0][0], 128, 16 + cb, kk, kg);
        }
        #pragma unroll
        for (int q = 0; q < 2; ++q) {
            int f = (q == 0) ? (wv * 2 + hy) : (8 + wv * 2 + hy);
            bf16x8 b = *(const bf16x8*)(WT + OFF_V + (size_t)(f * 4 + kk) * 512 + lane * 8);
            #pragma unroll
            for (int j = 0; j < 3; ++j) {
                aV[q][j][0] = __builtin_amdgcn_mfma_f32_16x16x32_bf16(av[j][0], b, aV[q][j][0], 0, 0, 0);
                aV[q][j][1] = __builtin_amdgcn_mfma_f32_16x16x32_bf16(av[j][1], b, aV[q][j][1], 0, 0, 0);
            }
        }
    }

    // out1 epilogue -> bf16 scratch
    {
        int w = wv * 32 + hy * 16 + cb;
        #pragma unroll
        for (int rg = 0; rg < 2; ++rg)
            #pragma unroll
            for (int j = 0; j < 4; ++j) {
                int row = rg * 16 + kg * 4 + j;
                int n = n0 + row;
                float g   = aG[rg][j];
                float s2r = sY[row][0];
                float w2x = sY[row][1], w2y = sY[row][2], w2z = sY[row][3];
                float P0 = aV[0][0][rg][j], P1 = aV[0][1][rg][j], P2 = aV[0][2][rg][j];
                float Q0 = aV[1][0][rg][j], Q1 = aV[1][1][rg][j], Q2 = aV[1][2][rg][j];
                float e0 = w2x * g + s2r * P0 + w2z * Q1 - w2y * Q2;
                float e1 = w2y * g + s2r * P1 + w2x * Q2 - w2z * Q0;
                float e2 = w2z * g + s2r * P2 + w2y * Q0 - w2x * Q1;
                unsigned short* sp = scr + (size_t)n * DIMX + M0 + 3 * w;
                sp[0] = f2bf(e0); sp[1] = f2bf(e1); sp[2] = f2bf(e2);
            }
    }
}

// ---------------------------------------------------------------------------
// k2_norm: fused stats+apply over bf16 scratch. Delta vs R15: 320 thr =
// 80 col-threads x 4 row-lanes, 8 cols/thread via one uint4 (16B) load.
// Thread t computes scales for columns t and t+320. Formulas identical.
// ---------------------------------------------------------------------------
__global__ __launch_bounds__(320)
void k2_norm(float* __restrict__ out, const unsigned short* __restrict__ scr,
             const int* __restrict__ batch,
             const float* __restrict__ mean_shift, const float* __restrict__ aw,
             const float* __restrict__ ab)
{
    __shared__ float sS[4][DIMX];
    __shared__ float sQ[4][DIMX];
    __shared__ float sScale[DIMX];
    __shared__ float sShift[DIMX];
    __shared__ int   sSE[2];

    const int g = blockIdx.x;
    const int t = threadIdx.x;
    if (t == 0) {
        sSE[0] = lower_bound_i(batch, N_ROWS, g);
        sSE[1] = lower_bound_i(batch, N_ROWS, g + 1);
    }
    __syncthreads();
    const int start = sSE[0], end = sSE[1];
    float cnt = (float)(end - start);
    if (cnt < 1.f) cnt = 1.f;

    const int rl = t / 80;      // row lane 0..3
    const int ct = t % 80;      // col thread
    const int c0 = ct * 8;      // owns cols [c0, c0+8)

    // pass 1: accumulate from bf16 scratch, one 16B load per row
    float s8[8] = {}, q8[8] = {};
    for (int n = start + rl; n < end; n += 4) {
        uint4 u = *(const uint4*)(scr + (size_t)n * DIMX + c0);
        float2 p0 = bf2x2(u.x), p1 = bf2x2(u.y), p2 = bf2x2(u.z), p3 = bf2x2(u.w);
        s8[0] += p0.x; q8[0] = fmaf(p0.x, p0.x, q8[0]);
        s8[1] += p0.y; q8[1] = fmaf(p0.y, p0.y, q8[1]);
        s8[2] += p1.x; q8[2] = fmaf(p1.x, p1.x, q8[2]);
        s8[3] += p1.y; q8[3] = fmaf(p1.y, p1.y, q8[3]);
        s8[4] += p2.x; q8[4] = fmaf(p2.x, p2.x, q8[4]);
        s8[5] += p2.y; q8[5] = fmaf(p2.y, p2.y, q8[5]);
        s8[6] += p3.x; q8[6] = fmaf(p3.x, p3.x, q8[6]);
        s8[7] += p3.y; q8[7] = fmaf(p3.y, p3.y, q8[7]);
    }
    #pragma unroll
    for (int i = 0; i < 8; ++i) { sS[rl][c0 + i] = s8[i]; sQ[rl][c0 + i] = q8[i]; }
    __syncthreads();

    // column totals: thread t owns columns t and t+320
    #pragma unroll
    for (int pass = 0; pass < 2; ++pass) {
        int c = t + pass * 320;
        float sum = sS[0][c] + sS[1][c] + sS[2][c] + sS[3][c];
        float sq  = sQ[0][c] + sQ[1][c] + sQ[2][c] + sQ[3][c];
        if (c < M0) {
            float mean = sum / cnt;
            float esq  = sq / cnt;
            float ms   = mean_shift[c];
            float var  = esq - 2.f * ms * mean * mean + ms * ms * mean * mean;
            float sc   = rsqrtf(var + EPSV) * aw[c];
            sScale[c] = sc;
            sShift[c] = ab[c] - mean * ms * sc;
        } else {
            sQ[0][c] = sq;
        }
    }
    __syncthreads();
    if (t < M1) {
        int w = t;
        float qq = sQ[0][M0 + 3 * w] + sQ[0][M0 + 3 * w + 1] + sQ[0][M0 + 3 * w + 2];
        float a1 = rsqrtf(qq / (3.f * cnt) + EPSV) * aw[M0 + w];
        sScale[M0 + 3 * w] = a1; sScale[M0 + 3 * w + 1] = a1; sScale[M0 + 3 * w + 2] = a1;
        sShift[M0 + 3 * w] = 0.f; sShift[M0 + 3 * w + 1] = 0.f; sShift[M0 + 3 * w + 2] = 0.f;
    }
    __syncthreads();

    // pass 2: apply (re-read scratch, L3-warm), write fp32 out
    const float4 sca = *(const float4*)&sScale[c0];
    const float4 scb = *(const float4*)&sScale[c0 + 4];
    const float4 sha = *(const float4*)&sShift[c0];
    const float4 shb = *(const float4*)&sShift[c0 + 4];
    for (int n = start + rl; n < end; n += 4) {
        uint4 u = *(const uint4*)(scr + (size_t)n * DIMX + c0);
        float2 p0 = bf2x2(u.x), p1 = bf2x2(u.y), p2 = bf2x2(u.z), p3 = bf2x2(u.w);
        float4 va = make_float4(fmaf(p0.x, sca.x, sha.x), fmaf(p0.y, sca.y, sha.y),
                                fmaf(p1.x, sca.z, sha.z), fmaf(p1.y, sca.w, sha.w));
        float4 vb = make_float4(fmaf(p2.x, scb.x, shb.x), fmaf(p2.y, scb.y, shb.y),
                                fmaf(p3.x, scb.z, shb.z), fmaf(p3.y, scb.w, shb.w));
        float* p = out + (size_t)n * DIMX + c0;
        *(float4*)p = va;
        *(float4*)(p + 4) = vb;
    }
}

// ---------------------------------------------------------------------------
extern "C" void kernel_launch(void* const* d_in, const int* in_sizes, int n_in,
                              void* d_out, int out_size, void* d_ws, size_t ws_size,
                              hipStream_t stream)
{
    const float* x     = (const float*)d_in[0];
    const float* y     = (const float*)d_in[1];
    const float* w000  = (const float*)d_in[2];
    const float* w011  = (const float*)d_in[3];
    const float* w101  = (const float*)d_in[4];
    const float* w110  = (const float*)d_in[5];
    const float* w111  = (const float*)d_in[6];
    const float* bias0 = (const float*)d_in[7];
    const float* mshift= (const float*)d_in[8];
    const float* aw    = (const float*)d_in[9];
    const float* ab    = (const float*)d_in[10];
    const int*   batch = (const int*)d_in[11];
    float* out = (float*)d_out;

    unsigned short* WT  = (unsigned short*)d_ws;
    unsigned short* scr = WT + WT_TOTAL;   // 100000*640 bf16 = 128 MB

    k0_pack<<<WT_TOTAL / 256, 256, 0, stream>>>(w000, w011, w101, w110, w111, WT);
    k1_mfma<<<(N_ROWS / BM) * 2, 256, 0, stream>>>(x, y, WT, bias0, scr);
    k2_norm<<<NG, 320, 0, stream>>>(out, scr, batch, mshift, aw, ab);
}

// Round 17
// 311.627 us; speedup vs baseline: 1.1729x; 1.1729x over previous
//
#include <hip/hip_runtime.h>
#include <math.h>

#define N_ROWS 100000
#define NG     2000
#define M0     256
#define M1     128
#define DIMX   640
#define EPSV   1e-5f
#define BM     32

#define INV_SQRT3 0.57735026918962576f
#define INV_SQRT2 0.70710678118654752f

#define OFF_U  0
#define OFF_D  98304
#define OFF_V  131072
#define WT_TOTAL 163840

typedef __attribute__((ext_vector_type(8))) short bf16x8;
typedef __attribute__((ext_vector_type(4))) float f32x4;

__device__ __forceinline__ unsigned short f2bf(float f) {
    union { float f; unsigned int u; } v; v.f = f;
    unsigned int r = v.u + 0x7fff + ((v.u >> 16) & 1);
    return (unsigned short)(r >> 16);
}
__device__ __forceinline__ float bf2f(unsigned short u) {
    union { unsigned int u; float f; } v; v.u = ((unsigned int)u) << 16; return v.f;
}

__device__ __forceinline__ int lower_bound_i(const int* __restrict__ b, int n, int key) {
    int lo = 0, hi = n;
    while (lo < hi) { int m = (lo + hi) >> 1; if (b[m] < key) lo = m + 1; else hi = m; }
    return lo;
}

// ---------------------------------------------------------------------------
// k0: pack weights -> bf16 per-MFMA-tile layout, scales folded. (R15 verbatim)
// ---------------------------------------------------------------------------
__global__ __launch_bounds__(256)
void k0_pack(const float* __restrict__ w000, const float* __restrict__ w011,
             const float* __restrict__ w101, const float* __restrict__ w110,
             const float* __restrict__ w111, unsigned short* __restrict__ WT)
{
    int i = blockIdx.x * 256 + threadIdx.x;
    if (i >= WT_TOTAL) return;
    int l = (i >> 3) & 63, e = i & 7;
    int lc = l & 15, lk = (l >> 4) << 3;
    float val;
    if (i < OFF_D) {
        int tile = i >> 9; int f = tile >> 3, kk = tile & 7;
        int col = f * 16 + lc, k = kk * 32 + lk + e;
        val = (col < 256) ? w000[k * 256 + col] : w011[k * 128 + (col - 256)];
    } else if (i < OFF_V) {
        int j = i - OFF_D; int tile = j >> 9; int f = tile >> 2, kk = tile & 3;
        int col = f * 16 + lc, k = kk * 32 + lk + e;
        val = w110[k * 256 + col] * INV_SQRT3;
    } else {
        int j = i - OFF_V; int tile = j >> 9; int f = tile >> 2, kk = tile & 3;
        int col = f * 16 + lc, k = kk * 32 + lk + e;
        val = (col < 128) ? w101[k * 128 + col]
                          : w111[k * 128 + (col - 128)] * INV_SQRT2;
    }
    WT[i] = f2bf(val);
}

__device__ __forceinline__ bf16x8 ldA(const unsigned short* base, int KW,
                                      int row, int kk, int kg)
{
    int off = row * KW + (((kk << 5) + (kg << 3)) ^ ((row & 7) << 3));
    return *(const bf16x8*)(base + off);
}

// ---------------------------------------------------------------------------
// k1: R15 verbatim (proven 181 us; bf16 scratch stores).
// ---------------------------------------------------------------------------
__global__ __launch_bounds__(256, 3)
void k1_mfma(const float* __restrict__ x, const float* __restrict__ y,
             const unsigned short* __restrict__ WT, const float* __restrict__ bias0,
             unsigned short* __restrict__ scr)
{
    __shared__ unsigned short xs1[BM][256];
    __shared__ unsigned short xv[3][BM][128];
    __shared__ unsigned short xd[BM][128];
    __shared__ float sY[BM][4];
    __shared__ float sBias[256];

    const int t    = threadIdx.x;
    const int lane = t & 63;
    const int wv   = t >> 6;
    const int cb   = lane & 15;
    const int kg   = lane >> 4;
    const int hy   = blockIdx.x & 1;
    const int n0   = (blockIdx.x >> 1) * BM;

    if (t < 128) sY[t >> 2][t & 3] = y[(size_t)(n0 + (t >> 2)) * 4 + (t & 3)];
    sBias[t] = bias0[t];

    // ---- stage x once: s1 and deinterleaved v1 ----
    #pragma unroll
    for (int i = 0; i < 8; ++i) {
        int idx = i * 256 + t;
        int r = idx >> 6, c4 = idx & 63;
        float4 v = *(const float4*)(x + (size_t)(n0 + r) * DIMX + c4 * 4);
        ushort4 o = { f2bf(v.x), f2bf(v.y), f2bf(v.z), f2bf(v.w) };
        *(ushort4*)&xs1[r][(c4 * 4) ^ ((r & 7) << 3)] = o;
    }
    #pragma unroll
    for (int i = 0; i < 4; ++i) {
        int idx = i * 256 + t;
        int r = idx >> 5, q = idx & 31;
        const float* vp = x + (size_t)(n0 + r) * DIMX + M0 + q * 12;
        float4 a = *(const float4*)vp;
        float4 b = *(const float4*)(vp + 4);
        float4 c = *(const float4*)(vp + 8);
        int off = (q * 4) ^ ((r & 7) << 3);
        ushort4 ox = { f2bf(a.x), f2bf(a.w), f2bf(b.z), f2bf(c.y) };
        ushort4 oy = { f2bf(a.y), f2bf(b.x), f2bf(b.w), f2bf(c.z) };
        ushort4 oz = { f2bf(a.z), f2bf(b.y), f2bf(c.x), f2bf(c.w) };
        *(ushort4*)&xv[0][r][off] = ox;
        *(ushort4*)&xv[1][r][off] = oy;
        *(ushort4*)&xv[2][r][off] = oz;
    }
    __syncthreads();

    // ---- d = v1 . v2 ----
    #pragma unroll
    for (int i = 0; i < 4; ++i) {
        int idx = i * 256 + t;
        int r = idx >> 5, q = idx & 31;
        int off = (q * 4) ^ ((r & 7) << 3);
        ushort4 ux = *(const ushort4*)&xv[0][r][off];
        ushort4 uy = *(const ushort4*)&xv[1][r][off];
        ushort4 uz = *(const ushort4*)&xv[2][r][off];
        float v2x = sY[r][1], v2y = sY[r][2], v2z = sY[r][3];
        ushort4 od;
        od.x = f2bf(bf2f(ux.x) * v2x + bf2f(uy.x) * v2y + bf2f(uz.x) * v2z);
        od.y = f2bf(bf2f(ux.y) * v2x + bf2f(uy.y) * v2y + bf2f(uz.y) * v2z);
        od.z = f2bf(bf2f(ux.z) * v2x + bf2f(uy.z) * v2y + bf2f(uz.z) * v2z);
        od.w = f2bf(bf2f(ux.w) * v2x + bf2f(uy.w) * v2y + bf2f(uz.w) * v2z);
        *(ushort4*)&xd[r][off] = od;
    }
    __syncthreads();

    float s2v[2][4];
    #pragma unroll
    for (int rg = 0; rg < 2; ++rg)
        #pragma unroll
        for (int j = 0; j < 4; ++j)
            s2v[rg][j] = sY[rg * 16 + kg * 4 + j][0];

    // ---- U phase: [out0_raw | G2] = s1 @ [W000 | W011], K=256 ----
    f32x4 aO[2][2];
    f32x4 aG[2];
    #pragma unroll
    for (int q = 0; q < 2; ++q) { aO[q][0] = (f32x4){0,0,0,0}; aO[q][1] = (f32x4){0,0,0,0}; }
    aG[0] = (f32x4){0,0,0,0}; aG[1] = (f32x4){0,0,0,0};

    #pragma unroll
    for (int kk = 0; kk < 8; ++kk) {
        bf16x8 a0 = ldA(&xs1[0][0], 256, cb, kk, kg);
        bf16x8 a1 = ldA(&xs1[0][0], 256, 16 + cb, kk, kg);
        #pragma unroll
        for (int q = 0; q < 3; ++q) {
            int f = (q < 2) ? (wv * 4 + hy * 2 + q) : (16 + wv * 2 + hy);
            bf16x8 b = *(const bf16x8*)(WT + OFF_U + (size_t)(f * 8 + kk) * 512 + lane * 8);
            if (q < 2) {
                aO[q][0] = __builtin_amdgcn_mfma_f32_16x16x32_bf16(a0, b, aO[q][0], 0, 0, 0);
                aO[q][1] = __builtin_amdgcn_mfma_f32_16x16x32_bf16(a1, b, aO[q][1], 0, 0, 0);
            } else {
                aG[0] = __builtin_amdgcn_mfma_f32_16x16x32_bf16(a0, b, aG[0], 0, 0, 0);
                aG[1] = __builtin_amdgcn_mfma_f32_16x16x32_bf16(a1, b, aG[1], 0, 0, 0);
            }
        }
    }

    #pragma unroll
    for (int q = 0; q < 2; ++q)
        #pragma unroll
        for (int rg = 0; rg < 2; ++rg)
            #pragma unroll
            for (int j = 0; j < 4; ++j)
                aO[q][rg][j] *= s2v[rg][j];

    #pragma unroll
    for (int kk = 0; kk < 4; ++kk) {
        bf16x8 a0 = ldA(&xd[0][0], 128, cb, kk, kg);
        bf16x8 a1 = ldA(&xd[0][0], 128, 16 + cb, kk, kg);
        #pragma unroll
        for (int q = 0; q < 2; ++q) {
            int f = wv * 4 + hy * 2 + q;
            bf16x8 b = *(const bf16x8*)(WT + OFF_D + (size_t)(f * 4 + kk) * 512 + lane * 8);
            aO[q][0] = __builtin_amdgcn_mfma_f32_16x16x32_bf16(a0, b, aO[q][0], 0, 0, 0);
            aO[q][1] = __builtin_amdgcn_mfma_f32_16x16x32_bf16(a1, b, aO[q][1], 0, 0, 0);
        }
    }

    // out0 epilogue -> bf16 scratch
    #pragma unroll
    for (int q = 0; q < 2; ++q) {
        int col = wv * 64 + hy * 32 + q * 16 + cb;
        float bb = sBias[col];
        #pragma unroll
        for (int rg = 0; rg < 2; ++rg)
            #pragma unroll
            for (int j = 0; j < 4; ++j) {
                int row = rg * 16 + kg * 4 + j;
                scr[(size_t)(n0 + row) * DIMX + col] = f2bf(aO[q][rg][j] + bb);
            }
    }

    // ---- V phase ----
    f32x4 aV[2][3][2];
    #pragma unroll
    for (int q = 0; q < 2; ++q)
        #pragma unroll
        for (int j = 0; j < 3; ++j) { aV[q][j][0] = (f32x4){0,0,0,0}; aV[q][j][1] = (f32x4){0,0,0,0}; }

    #pragma unroll
    for (int kk = 0; kk < 4; ++kk) {
        bf16x8 av[3][2];
        #pragma unroll
        for (int j = 0; j < 3; ++j) {
            av[j][0] = ldA(&xv[j][0][0], 128, cb, kk, kg);
            av[j][1] = ldA(&xv[j][0][0], 128, 16 + cb, kk, kg);
        }
        #pragma unroll
        for (int q = 0; q < 2; ++q) {
            int f = (q == 0) ? (wv * 2 + hy) : (8 + wv * 2 + hy);
            bf16x8 b = *(const bf16x8*)(WT + OFF_V + (size_t)(f * 4 + kk) * 512 + lane * 8);
            #pragma unroll
            for (int j = 0; j < 3; ++j) {
                aV[q][j][0] = __builtin_amdgcn_mfma_f32_16x16x32_bf16(av[j][0], b, aV[q][j][0], 0, 0, 0);
                aV[q][j][1] = __builtin_amdgcn_mfma_f32_16x16x32_bf16(av[j][1], b, aV[q][j][1], 0, 0, 0);
            }
        }
    }

    // out1 epilogue -> bf16 scratch
    {
        int w = wv * 32 + hy * 16 + cb;
        #pragma unroll
        for (int rg = 0; rg < 2; ++rg)
            #pragma unroll
            for (int j = 0; j < 4; ++j) {
                int row = rg * 16 + kg * 4 + j;
                int n = n0 + row;
                float g   = aG[rg][j];
                float s2r = sY[row][0];
                float w2x = sY[row][1], w2y = sY[row][2], w2z = sY[row][3];
                float P0 = aV[0][0][rg][j], P1 = aV[0][1][rg][j], P2 = aV[0][2][rg][j];
                float Q0 = aV[1][0][rg][j], Q1 = aV[1][1][rg][j], Q2 = aV[1][2][rg][j];
                float e0 = w2x * g + s2r * P0 + w2z * Q1 - w2y * Q2;
                float e1 = w2y * g + s2r * P1 + w2x * Q2 - w2z * Q0;
                float e2 = w2z * g + s2r * P2 + w2y * Q0 - w2x * Q1;
                unsigned short* sp = scr + (size_t)n * DIMX + M0 + 3 * w;
                sp[0] = f2bf(e0); sp[1] = f2bf(e1); sp[2] = f2bf(e2);
            }
    }
}

// ---------------------------------------------------------------------------
// k2_norm: R15 verbatim (proven 125 us). 640 thr = 160 col x 4 row-lanes,
// fused stats+apply; reads bf16 scratch (ushort4), writes fp32 out.
// ---------------------------------------------------------------------------
__global__ __launch_bounds__(640)
void k2_norm(float* __restrict__ out, const unsigned short* __restrict__ scr,
             const int* __restrict__ batch,
             const float* __restrict__ mean_shift, const float* __restrict__ aw,
             const float* __restrict__ ab)
{
    __shared__ float sS[4][DIMX];
    __shared__ float sQ[4][DIMX];
    __shared__ float sScale[DIMX];
    __shared__ float sShift[DIMX];
    __shared__ int   sSE[2];

    const int g = blockIdx.x;
    const int t = threadIdx.x;
    if (t == 0) {
        sSE[0] = lower_bound_i(batch, N_ROWS, g);
        sSE[1] = lower_bound_i(batch, N_ROWS, g + 1);
    }
    __syncthreads();
    const int start = sSE[0], end = sSE[1];
    float cnt = (float)(end - start);
    if (cnt < 1.f) cnt = 1.f;

    const int rl = t / 160;     // row lane 0..3
    const int ct = t % 160;     // col thread
    const int c0 = ct * 4;

    // pass 1: accumulate from bf16 scratch
    float4 s4 = make_float4(0.f, 0.f, 0.f, 0.f);
    float4 q4 = make_float4(0.f, 0.f, 0.f, 0.f);
    for (int n = start + rl; n < end; n += 4) {
        ushort4 u = *(const ushort4*)(scr + (size_t)n * DIMX + c0);
        float4 v = make_float4(bf2f(u.x), bf2f(u.y), bf2f(u.z), bf2f(u.w));
        s4.x += v.x; q4.x = fmaf(v.x, v.x, q4.x);
        s4.y += v.y; q4.y = fmaf(v.y, v.y, q4.y);
        s4.z += v.z; q4.z = fmaf(v.z, v.z, q4.z);
        s4.w += v.w; q4.w = fmaf(v.w, v.w, q4.w);
    }
    *(float4*)&sS[rl][c0] = s4;
    *(float4*)&sQ[rl][c0] = q4;
    __syncthreads();

    // per-column totals (thread t owns column t)
    float sum = sS[0][t] + sS[1][t] + sS[2][t] + sS[3][t];
    float sq  = sQ[0][t] + sQ[1][t] + sQ[2][t] + sQ[3][t];

    if (t < M0) {
        float mean = sum / cnt;
        float esq  = sq / cnt;
        float ms   = mean_shift[t];
        float var  = esq - 2.f * ms * mean * mean + ms * ms * mean * mean;
        float sc   = rsqrtf(var + EPSV) * aw[t];
        sScale[t] = sc;
        sShift[t] = ab[t] - mean * ms * sc;
    } else {
        sQ[0][t] = sq;
    }
    __syncthreads();
    if (t >= M0) {
        int w = (t - M0) / 3;
        float qq = sQ[0][M0 + 3 * w] + sQ[0][M0 + 3 * w + 1] + sQ[0][M0 + 3 * w + 2];
        sScale[t] = rsqrtf(qq / (3.f * cnt) + EPSV) * aw[M0 + w];
        sShift[t] = 0.f;
    }
    __syncthreads();

    // pass 2: apply (read scratch again — L3-warm), write fp32 out
    const float4 sc4 = *(const float4*)&sScale[c0];
    const float4 sh4 = *(const float4*)&sShift[c0];
    for (int n = start + rl; n < end; n += 4) {
        ushort4 u = *(const ushort4*)(scr + (size_t)n * DIMX + c0);
        float4 v = make_float4(bf2f(u.x), bf2f(u.y), bf2f(u.z), bf2f(u.w));
        v.x = fmaf(v.x, sc4.x, sh4.x);
        v.y = fmaf(v.y, sc4.y, sh4.y);
        v.z = fmaf(v.z, sc4.z, sh4.z);
        v.w = fmaf(v.w, sc4.w, sh4.w);
        *(float4*)(out + (size_t)n * DIMX + c0) = v;
    }
}

// ---------------------------------------------------------------------------
extern "C" void kernel_launch(void* const* d_in, const int* in_sizes, int n_in,
                              void* d_out, int out_size, void* d_ws, size_t ws_size,
                              hipStream_t stream)
{
    const float* x     = (const float*)d_in[0];
    const float* y     = (const float*)d_in[1];
    const float* w000  = (const float*)d_in[2];
    const float* w011  = (const float*)d_in[3];
    const float* w101  = (const float*)d_in[4];
    const float* w110  = (const float*)d_in[5];
    const float* w111  = (const float*)d_in[6];
    const float* bias0 = (const float*)d_in[7];
    const float* mshift= (const float*)d_in[8];
    const float* aw    = (const float*)d_in[9];
    const float* ab    = (const float*)d_in[10];
    const int*   batch = (const int*)d_in[11];
    float* out = (float*)d_out;

    unsigned short* WT  = (unsigned short*)d_ws;
    unsigned short* scr = WT + WT_TOTAL;   // 100000*640 bf16 = 128 MB

    k0_pack<<<WT_TOTAL / 256, 256, 0, stream>>>(w000, w011, w101, w110, w111, WT);
    k1_mfma<<<(N_ROWS / BM) * 2, 256, 0, stream>>>(x, y, WT, bias0, scr);
    k2_norm<<<NG, 640, 0, stream>>>(out, scr, batch, mshift, aw, ab);
}

// Round 18
// 306.733 us; speedup vs baseline: 1.1916x; 1.0160x over previous
//
#include <hip/hip_runtime.h>
#include <math.h>

#define N_ROWS 100000
#define NG     2000
#define M0     256
#define M1     128
#define DIMX   640
#define EPSV   1e-5f
#define BM     32

#define INV_SQRT3 0.57735026918962576f
#define INV_SQRT2 0.70710678118654752f

#define OFF_U  0
#define OFF_D  98304
#define OFF_V  131072
#define WT_TOTAL 163840

typedef __attribute__((ext_vector_type(8))) short bf16x8;
typedef __attribute__((ext_vector_type(4))) float f32x4;

__device__ __forceinline__ unsigned short f2bf(float f) {
    union { float f; unsigned int u; } v; v.f = f;
    unsigned int r = v.u + 0x7fff + ((v.u >> 16) & 1);
    return (unsigned short)(r >> 16);
}
__device__ __forceinline__ float bf2f(unsigned short u) {
    union { unsigned int u; float f; } v; v.u = ((unsigned int)u) << 16; return v.f;
}

__device__ __forceinline__ int lower_bound_i(const int* __restrict__ b, int n, int key) {
    int lo = 0, hi = n;
    while (lo < hi) { int m = (lo + hi) >> 1; if (b[m] < key) lo = m + 1; else hi = m; }
    return lo;
}

// ---------------------------------------------------------------------------
// k0: pack weights -> bf16 per-MFMA-tile layout, scales folded. (R17 verbatim)
// ---------------------------------------------------------------------------
__global__ __launch_bounds__(256)
void k0_pack(const float* __restrict__ w000, const float* __restrict__ w011,
             const float* __restrict__ w101, const float* __restrict__ w110,
             const float* __restrict__ w111, unsigned short* __restrict__ WT)
{
    int i = blockIdx.x * 256 + threadIdx.x;
    if (i >= WT_TOTAL) return;
    int l = (i >> 3) & 63, e = i & 7;
    int lc = l & 15, lk = (l >> 4) << 3;
    float val;
    if (i < OFF_D) {
        int tile = i >> 9; int f = tile >> 3, kk = tile & 7;
        int col = f * 16 + lc, k = kk * 32 + lk + e;
        val = (col < 256) ? w000[k * 256 + col] : w011[k * 128 + (col - 256)];
    } else if (i < OFF_V) {
        int j = i - OFF_D; int tile = j >> 9; int f = tile >> 2, kk = tile & 3;
        int col = f * 16 + lc, k = kk * 32 + lk + e;
        val = w110[k * 256 + col] * INV_SQRT3;
    } else {
        int j = i - OFF_V; int tile = j >> 9; int f = tile >> 2, kk = tile & 3;
        int col = f * 16 + lc, k = kk * 32 + lk + e;
        val = (col < 128) ? w101[k * 128 + col]
                          : w111[k * 128 + (col - 128)] * INV_SQRT2;
    }
    WT[i] = f2bf(val);
}

__device__ __forceinline__ bf16x8 ldA(const unsigned short* base, int KW,
                                      int row, int kk, int kg)
{
    int off = row * KW + (((kk << 5) + (kg << 3)) ^ ((row & 7) << 3));
    return *(const bf16x8*)(base + off);
}

// ---------------------------------------------------------------------------
// k1: R17 verbatim + ONE delta: s_setprio(1)/(0) around each kk-iteration's
// MFMA cluster (T5; scheduler hint only, zero correctness risk). Waves run
// barrier-free through U/D/V, so the CU scheduler has phase diversity to
// arbitrate (attn-like regime, m191).
// ---------------------------------------------------------------------------
__global__ __launch_bounds__(256, 3)
void k1_mfma(const float* __restrict__ x, const float* __restrict__ y,
             const unsigned short* __restrict__ WT, const float* __restrict__ bias0,
             unsigned short* __restrict__ scr)
{
    __shared__ unsigned short xs1[BM][256];
    __shared__ unsigned short xv[3][BM][128];
    __shared__ unsigned short xd[BM][128];
    __shared__ float sY[BM][4];
    __shared__ float sBias[256];

    const int t    = threadIdx.x;
    const int lane = t & 63;
    const int wv   = t >> 6;
    const int cb   = lane & 15;
    const int kg   = lane >> 4;
    const int hy   = blockIdx.x & 1;
    const int n0   = (blockIdx.x >> 1) * BM;

    if (t < 128) sY[t >> 2][t & 3] = y[(size_t)(n0 + (t >> 2)) * 4 + (t & 3)];
    sBias[t] = bias0[t];

    // ---- stage x once: s1 and deinterleaved v1 ----
    #pragma unroll
    for (int i = 0; i < 8; ++i) {
        int idx = i * 256 + t;
        int r = idx >> 6, c4 = idx & 63;
        float4 v = *(const float4*)(x + (size_t)(n0 + r) * DIMX + c4 * 4);
        ushort4 o = { f2bf(v.x), f2bf(v.y), f2bf(v.z), f2bf(v.w) };
        *(ushort4*)&xs1[r][(c4 * 4) ^ ((r & 7) << 3)] = o;
    }
    #pragma unroll
    for (int i = 0; i < 4; ++i) {
        int idx = i * 256 + t;
        int r = idx >> 5, q = idx & 31;
        const float* vp = x + (size_t)(n0 + r) * DIMX + M0 + q * 12;
        float4 a = *(const float4*)vp;
        float4 b = *(const float4*)(vp + 4);
        float4 c = *(const float4*)(vp + 8);
        int off = (q * 4) ^ ((r & 7) << 3);
        ushort4 ox = { f2bf(a.x), f2bf(a.w), f2bf(b.z), f2bf(c.y) };
        ushort4 oy = { f2bf(a.y), f2bf(b.x), f2bf(b.w), f2bf(c.z) };
        ushort4 oz = { f2bf(a.z), f2bf(b.y), f2bf(c.x), f2bf(c.w) };
        *(ushort4*)&xv[0][r][off] = ox;
        *(ushort4*)&xv[1][r][off] = oy;
        *(ushort4*)&xv[2][r][off] = oz;
    }
    __syncthreads();

    // ---- d = v1 . v2 ----
    #pragma unroll
    for (int i = 0; i < 4; ++i) {
        int idx = i * 256 + t;
        int r = idx >> 5, q = idx & 31;
        int off = (q * 4) ^ ((r & 7) << 3);
        ushort4 ux = *(const ushort4*)&xv[0][r][off];
        ushort4 uy = *(const ushort4*)&xv[1][r][off];
        ushort4 uz = *(const ushort4*)&xv[2][r][off];
        float v2x = sY[r][1], v2y = sY[r][2], v2z = sY[r][3];
        ushort4 od;
        od.x = f2bf(bf2f(ux.x) * v2x + bf2f(uy.x) * v2y + bf2f(uz.x) * v2z);
        od.y = f2bf(bf2f(ux.y) * v2x + bf2f(uy.y) * v2y + bf2f(uz.y) * v2z);
        od.z = f2bf(bf2f(ux.z) * v2x + bf2f(uy.z) * v2y + bf2f(uz.z) * v2z);
        od.w = f2bf(bf2f(ux.w) * v2x + bf2f(uy.w) * v2y + bf2f(uz.w) * v2z);
        *(ushort4*)&xd[r][off] = od;
    }
    __syncthreads();

    float s2v[2][4];
    #pragma unroll
    for (int rg = 0; rg < 2; ++rg)
        #pragma unroll
        for (int j = 0; j < 4; ++j)
            s2v[rg][j] = sY[rg * 16 + kg * 4 + j][0];

    // ---- U phase: [out0_raw | G2] = s1 @ [W000 | W011], K=256 ----
    f32x4 aO[2][2];
    f32x4 aG[2];
    #pragma unroll
    for (int q = 0; q < 2; ++q) { aO[q][0] = (f32x4){0,0,0,0}; aO[q][1] = (f32x4){0,0,0,0}; }
    aG[0] = (f32x4){0,0,0,0}; aG[1] = (f32x4){0,0,0,0};

    #pragma unroll
    for (int kk = 0; kk < 8; ++kk) {
        bf16x8 a0 = ldA(&xs1[0][0], 256, cb, kk, kg);
        bf16x8 a1 = ldA(&xs1[0][0], 256, 16 + cb, kk, kg);
        __builtin_amdgcn_s_setprio(1);
        #pragma unroll
        for (int q = 0; q < 3; ++q) {
            int f = (q < 2) ? (wv * 4 + hy * 2 + q) : (16 + wv * 2 + hy);
            bf16x8 b = *(const bf16x8*)(WT + OFF_U + (size_t)(f * 8 + kk) * 512 + lane * 8);
            if (q < 2) {
                aO[q][0] = __builtin_amdgcn_mfma_f32_16x16x32_bf16(a0, b, aO[q][0], 0, 0, 0);
                aO[q][1] = __builtin_amdgcn_mfma_f32_16x16x32_bf16(a1, b, aO[q][1], 0, 0, 0);
            } else {
                aG[0] = __builtin_amdgcn_mfma_f32_16x16x32_bf16(a0, b, aG[0], 0, 0, 0);
                aG[1] = __builtin_amdgcn_mfma_f32_16x16x32_bf16(a1, b, aG[1], 0, 0, 0);
            }
        }
        __builtin_amdgcn_s_setprio(0);
    }

    #pragma unroll
    for (int q = 0; q < 2; ++q)
        #pragma unroll
        for (int rg = 0; rg < 2; ++rg)
            #pragma unroll
            for (int j = 0; j < 4; ++j)
                aO[q][rg][j] *= s2v[rg][j];

    #pragma unroll
    for (int kk = 0; kk < 4; ++kk) {
        bf16x8 a0 = ldA(&xd[0][0], 128, cb, kk, kg);
        bf16x8 a1 = ldA(&xd[0][0], 128, 16 + cb, kk, kg);
        __builtin_amdgcn_s_setprio(1);
        #pragma unroll
        for (int q = 0; q < 2; ++q) {
            int f = wv * 4 + hy * 2 + q;
            bf16x8 b = *(const bf16x8*)(WT + OFF_D + (size_t)(f * 4 + kk) * 512 + lane * 8);
            aO[q][0] = __builtin_amdgcn_mfma_f32_16x16x32_bf16(a0, b, aO[q][0], 0, 0, 0);
            aO[q][1] = __builtin_amdgcn_mfma_f32_16x16x32_bf16(a1, b, aO[q][1], 0, 0, 0);
        }
        __builtin_amdgcn_s_setprio(0);
    }

    // out0 epilogue -> bf16 scratch
    #pragma unroll
    for (int q = 0; q < 2; ++q) {
        int col = wv * 64 + hy * 32 + q * 16 + cb;
        float bb = sBias[col];
        #pragma unroll
        for (int rg = 0; rg < 2; ++rg)
            #pragma unroll
            for (int j = 0; j < 4; ++j) {
                int row = rg * 16 + kg * 4 + j;
                scr[(size_t)(n0 + row) * DIMX + col] = f2bf(aO[q][rg][j] + bb);
            }
    }

    // ---- V phase ----
    f32x4 aV[2][3][2];
    #pragma unroll
    for (int q = 0; q < 2; ++q)
        #pragma unroll
        for (int j = 0; j < 3; ++j) { aV[q][j][0] = (f32x4){0,0,0,0}; aV[q][j][1] = (f32x4){0,0,0,0}; }

    #pragma unroll
    for (int kk = 0; kk < 4; ++kk) {
        bf16x8 av[3][2];
        #pragma unroll
        for (int j = 0; j < 3; ++j) {
            av[j][0] = ldA(&xv[j][0][0], 128, cb, kk, kg);
            av[j][1] = ldA(&xv[j][0][0], 128, 16 + cb, kk, kg);
        }
        __builtin_amdgcn_s_setprio(1);
        #pragma unroll
        for (int q = 0; q < 2; ++q) {
            int f = (q == 0) ? (wv * 2 + hy) : (8 + wv * 2 + hy);
            bf16x8 b = *(const bf16x8*)(WT + OFF_V + (size_t)(f * 4 + kk) * 512 + lane * 8);
            #pragma unroll
            for (int j = 0; j < 3; ++j) {
                aV[q][j][0] = __builtin_amdgcn_mfma_f32_16x16x32_bf16(av[j][0], b, aV[q][j][0], 0, 0, 0);
                aV[q][j][1] = __builtin_amdgcn_mfma_f32_16x16x32_bf16(av[j][1], b, aV[q][j][1], 0, 0, 0);
            }
        }
        __builtin_amdgcn_s_setprio(0);
    }

    // out1 epilogue -> bf16 scratch
    {
        int w = wv * 32 + hy * 16 + cb;
        #pragma unroll
        for (int rg = 0; rg < 2; ++rg)
            #pragma unroll
            for (int j = 0; j < 4; ++j) {
                int row = rg * 16 + kg * 4 + j;
                int n = n0 + row;
                float g   = aG[rg][j];
                float s2r = sY[row][0];
                float w2x = sY[row][1], w2y = sY[row][2], w2z = sY[row][3];
                float P0 = aV[0][0][rg][j], P1 = aV[0][1][rg][j], P2 = aV[0][2][rg][j];
                float Q0 = aV[1][0][rg][j], Q1 = aV[1][1][rg][j], Q2 = aV[1][2][rg][j];
                float e0 = w2x * g + s2r * P0 + w2z * Q1 - w2y * Q2;
                float e1 = w2y * g + s2r * P1 + w2x * Q2 - w2z * Q0;
                float e2 = w2z * g + s2r * P2 + w2y * Q0 - w2x * Q1;
                unsigned short* sp = scr + (size_t)n * DIMX + M0 + 3 * w;
                sp[0] = f2bf(e0); sp[1] = f2bf(e1); sp[2] = f2bf(e2);
            }
    }
}

// ---------------------------------------------------------------------------
// k2_norm: R17 verbatim (proven ~125 us).
// ---------------------------------------------------------------------------
__global__ __launch_bounds__(640)
void k2_norm(float* __restrict__ out, const unsigned short* __restrict__ scr,
             const int* __restrict__ batch,
             const float* __restrict__ mean_shift, const float* __restrict__ aw,
             const float* __restrict__ ab)
{
    __shared__ float sS[4][DIMX];
    __shared__ float sQ[4][DIMX];
    __shared__ float sScale[DIMX];
    __shared__ float sShift[DIMX];
    __shared__ int   sSE[2];

    const int g = blockIdx.x;
    const int t = threadIdx.x;
    if (t == 0) {
        sSE[0] = lower_bound_i(batch, N_ROWS, g);
        sSE[1] = lower_bound_i(batch, N_ROWS, g + 1);
    }
    __syncthreads();
    const int start = sSE[0], end = sSE[1];
    float cnt = (float)(end - start);
    if (cnt < 1.f) cnt = 1.f;

    const int rl = t / 160;     // row lane 0..3
    const int ct = t % 160;     // col thread
    const int c0 = ct * 4;

    // pass 1: accumulate from bf16 scratch
    float4 s4 = make_float4(0.f, 0.f, 0.f, 0.f);
    float4 q4 = make_float4(0.f, 0.f, 0.f, 0.f);
    for (int n = start + rl; n < end; n += 4) {
        ushort4 u = *(const ushort4*)(scr + (size_t)n * DIMX + c0);
        float4 v = make_float4(bf2f(u.x), bf2f(u.y), bf2f(u.z), bf2f(u.w));
        s4.x += v.x; q4.x = fmaf(v.x, v.x, q4.x);
        s4.y += v.y; q4.y = fmaf(v.y, v.y, q4.y);
        s4.z += v.z; q4.z = fmaf(v.z, v.z, q4.z);
        s4.w += v.w; q4.w = fmaf(v.w, v.w, q4.w);
    }
    *(float4*)&sS[rl][c0] = s4;
    *(float4*)&sQ[rl][c0] = q4;
    __syncthreads();

    // per-column totals (thread t owns column t)
    float sum = sS[0][t] + sS[1][t] + sS[2][t] + sS[3][t];
    float sq  = sQ[0][t] + sQ[1][t] + sQ[2][t] + sQ[3][t];

    if (t < M0) {
        float mean = sum / cnt;
        float esq  = sq / cnt;
        float ms   = mean_shift[t];
        float var  = esq - 2.f * ms * mean * mean + ms * ms * mean * mean;
        float sc   = rsqrtf(var + EPSV) * aw[t];
        sScale[t] = sc;
        sShift[t] = ab[t] - mean * ms * sc;
    } else {
        sQ[0][t] = sq;
    }
    __syncthreads();
    if (t >= M0) {
        int w = (t - M0) / 3;
        float qq = sQ[0][M0 + 3 * w] + sQ[0][M0 + 3 * w + 1] + sQ[0][M0 + 3 * w + 2];
        sScale[t] = rsqrtf(qq / (3.f * cnt) + EPSV) * aw[M0 + w];
        sShift[t] = 0.f;
    }
    __syncthreads();

    // pass 2: apply (read scratch again — L3-warm), write fp32 out
    const float4 sc4 = *(const float4*)&sScale[c0];
    const float4 sh4 = *(const float4*)&sShift[c0];
    for (int n = start + rl; n < end; n += 4) {
        ushort4 u = *(const ushort4*)(scr + (size_t)n * DIMX + c0);
        float4 v = make_float4(bf2f(u.x), bf2f(u.y), bf2f(u.z), bf2f(u.w));
        v.x = fmaf(v.x, sc4.x, sh4.x);
        v.y = fmaf(v.y, sc4.y, sh4.y);
        v.z = fmaf(v.z, sc4.z, sh4.z);
        v.w = fmaf(v.w, sc4.w, sh4.w);
        *(float4*)(out + (size_t)n * DIMX + c0) = v;
    }
}

// ---------------------------------------------------------------------------
extern "C" void kernel_launch(void* const* d_in, const int* in_sizes, int n_in,
                              void* d_out, int out_size, void* d_ws, size_t ws_size,
                              hipStream_t stream)
{
    const float* x     = (const float*)d_in[0];
    const float* y     = (const float*)d_in[1];
    const float* w000  = (const float*)d_in[2];
    const float* w011  = (const float*)d_in[3];
    const float* w101  = (const float*)d_in[4];
    const float* w110  = (const float*)d_in[5];
    const float* w111  = (const float*)d_in[6];
    const float* bias0 = (const float*)d_in[7];
    const float* mshift= (const float*)d_in[8];
    const float* aw    = (const float*)d_in[9];
    const float* ab    = (const float*)d_in[10];
    const int*   batch = (const int*)d_in[11];
    float* out = (float*)d_out;

    unsigned short* WT  = (unsigned short*)d_ws;
    unsigned short* scr = WT + WT_TOTAL;   // 100000*640 bf16 = 128 MB

    k0_pack<<<WT_TOTAL / 256, 256, 0, stream>>>(w000, w011, w101, w110, w111, WT);
    k1_mfma<<<(N_ROWS / BM) * 2, 256, 0, stream>>>(x, y, WT, bias0, scr);
    k2_norm<<<NG, 640, 0, stream>>>(out, scr, batch, mshift, aw, ab);
}

// Round 19
// 306.469 us; speedup vs baseline: 1.1927x; 1.0009x over previous
//
#include <hip/hip_runtime.h>
#include <math.h>

#define N_ROWS 100000
#define NG     2000
#define M0     256
#define M1     128
#define DIMX   640
#define EPSV   1e-5f
#define BM     32

#define INV_SQRT3 0.57735026918962576f
#define INV_SQRT2 0.70710678118654752f

#define OFF_U  0
#define OFF_D  98304
#define OFF_V  131072
#define WT_TOTAL 163840

typedef __attribute__((ext_vector_type(8))) short bf16x8;
typedef __attribute__((ext_vector_type(4))) float f32x4;

__device__ __forceinline__ unsigned short f2bf(float f) {
    union { float f; unsigned int u; } v; v.f = f;
    unsigned int r = v.u + 0x7fff + ((v.u >> 16) & 1);
    return (unsigned short)(r >> 16);
}
__device__ __forceinline__ float bf2f(unsigned short u) {
    union { unsigned int u; float f; } v; v.u = ((unsigned int)u) << 16; return v.f;
}

__device__ __forceinline__ int lower_bound_i(const int* __restrict__ b, int n, int key) {
    int lo = 0, hi = n;
    while (lo < hi) { int m = (lo + hi) >> 1; if (b[m] < key) lo = m + 1; else hi = m; }
    return lo;
}

// ---------------------------------------------------------------------------
// k0: pack weights -> bf16 per-MFMA-tile layout, scales folded.
// ---------------------------------------------------------------------------
__global__ __launch_bounds__(256)
void k0_pack(const float* __restrict__ w000, const float* __restrict__ w011,
             const float* __restrict__ w101, const float* __restrict__ w110,
             const float* __restrict__ w111, unsigned short* __restrict__ WT)
{
    int i = blockIdx.x * 256 + threadIdx.x;
    if (i >= WT_TOTAL) return;
    int l = (i >> 3) & 63, e = i & 7;
    int lc = l & 15, lk = (l >> 4) << 3;
    float val;
    if (i < OFF_D) {
        int tile = i >> 9; int f = tile >> 3, kk = tile & 7;
        int col = f * 16 + lc, k = kk * 32 + lk + e;
        val = (col < 256) ? w000[k * 256 + col] : w011[k * 128 + (col - 256)];
    } else if (i < OFF_V) {
        int j = i - OFF_D; int tile = j >> 9; int f = tile >> 2, kk = tile & 3;
        int col = f * 16 + lc, k = kk * 32 + lk + e;
        val = w110[k * 256 + col] * INV_SQRT3;
    } else {
        int j = i - OFF_V; int tile = j >> 9; int f = tile >> 2, kk = tile & 3;
        int col = f * 16 + lc, k = kk * 32 + lk + e;
        val = (col < 128) ? w101[k * 128 + col]
                          : w111[k * 128 + (col - 128)] * INV_SQRT2;
    }
    WT[i] = f2bf(val);
}

__device__ __forceinline__ bf16x8 ldA(const unsigned short* base, int KW,
                                      int row, int kk, int kg)
{
    int off = row * KW + (((kk << 5) + (kg << 3)) ^ ((row & 7) << 3));
    return *(const bf16x8*)(base + off);
}

// ---------------------------------------------------------------------------
// k1: final configuration (R18). BM=32, hy column split, bf16 scratch stores,
// s_setprio(1)/(0) around each kk-iteration's MFMA cluster.
// ---------------------------------------------------------------------------
__global__ __launch_bounds__(256, 3)
void k1_mfma(const float* __restrict__ x, const float* __restrict__ y,
             const unsigned short* __restrict__ WT, const float* __restrict__ bias0,
             unsigned short* __restrict__ scr)
{
    __shared__ unsigned short xs1[BM][256];
    __shared__ unsigned short xv[3][BM][128];
    __shared__ unsigned short xd[BM][128];
    __shared__ float sY[BM][4];
    __shared__ float sBias[256];

    const int t    = threadIdx.x;
    const int lane = t & 63;
    const int wv   = t >> 6;
    const int cb   = lane & 15;
    const int kg   = lane >> 4;
    const int hy   = blockIdx.x & 1;
    const int n0   = (blockIdx.x >> 1) * BM;

    if (t < 128) sY[t >> 2][t & 3] = y[(size_t)(n0 + (t >> 2)) * 4 + (t & 3)];
    sBias[t] = bias0[t];

    // ---- stage x once: s1 and deinterleaved v1 ----
    #pragma unroll
    for (int i = 0; i < 8; ++i) {
        int idx = i * 256 + t;
        int r = idx >> 6, c4 = idx & 63;
        float4 v = *(const float4*)(x + (size_t)(n0 + r) * DIMX + c4 * 4);
        ushort4 o = { f2bf(v.x), f2bf(v.y), f2bf(v.z), f2bf(v.w) };
        *(ushort4*)&xs1[r][(c4 * 4) ^ ((r & 7) << 3)] = o;
    }
    #pragma unroll
    for (int i = 0; i < 4; ++i) {
        int idx = i * 256 + t;
        int r = idx >> 5, q = idx & 31;
        const float* vp = x + (size_t)(n0 + r) * DIMX + M0 + q * 12;
        float4 a = *(const float4*)vp;
        float4 b = *(const float4*)(vp + 4);
        float4 c = *(const float4*)(vp + 8);
        int off = (q * 4) ^ ((r & 7) << 3);
        ushort4 ox = { f2bf(a.x), f2bf(a.w), f2bf(b.z), f2bf(c.y) };
        ushort4 oy = { f2bf(a.y), f2bf(b.x), f2bf(b.w), f2bf(c.z) };
        ushort4 oz = { f2bf(a.z), f2bf(b.y), f2bf(c.x), f2bf(c.w) };
        *(ushort4*)&xv[0][r][off] = ox;
        *(ushort4*)&xv[1][r][off] = oy;
        *(ushort4*)&xv[2][r][off] = oz;
    }
    __syncthreads();

    // ---- d = v1 . v2 ----
    #pragma unroll
    for (int i = 0; i < 4; ++i) {
        int idx = i * 256 + t;
        int r = idx >> 5, q = idx & 31;
        int off = (q * 4) ^ ((r & 7) << 3);
        ushort4 ux = *(const ushort4*)&xv[0][r][off];
        ushort4 uy = *(const ushort4*)&xv[1][r][off];
        ushort4 uz = *(const ushort4*)&xv[2][r][off];
        float v2x = sY[r][1], v2y = sY[r][2], v2z = sY[r][3];
        ushort4 od;
        od.x = f2bf(bf2f(ux.x) * v2x + bf2f(uy.x) * v2y + bf2f(uz.x) * v2z);
        od.y = f2bf(bf2f(ux.y) * v2x + bf2f(uy.y) * v2y + bf2f(uz.y) * v2z);
        od.z = f2bf(bf2f(ux.z) * v2x + bf2f(uy.z) * v2y + bf2f(uz.z) * v2z);
        od.w = f2bf(bf2f(ux.w) * v2x + bf2f(uy.w) * v2y + bf2f(uz.w) * v2z);
        *(ushort4*)&xd[r][off] = od;
    }
    __syncthreads();

    float s2v[2][4];
    #pragma unroll
    for (int rg = 0; rg < 2; ++rg)
        #pragma unroll
        for (int j = 0; j < 4; ++j)
            s2v[rg][j] = sY[rg * 16 + kg * 4 + j][0];

    // ---- U phase: [out0_raw | G2] = s1 @ [W000 | W011], K=256 ----
    f32x4 aO[2][2];
    f32x4 aG[2];
    #pragma unroll
    for (int q = 0; q < 2; ++q) { aO[q][0] = (f32x4){0,0,0,0}; aO[q][1] = (f32x4){0,0,0,0}; }
    aG[0] = (f32x4){0,0,0,0}; aG[1] = (f32x4){0,0,0,0};

    #pragma unroll
    for (int kk = 0; kk < 8; ++kk) {
        bf16x8 a0 = ldA(&xs1[0][0], 256, cb, kk, kg);
        bf16x8 a1 = ldA(&xs1[0][0], 256, 16 + cb, kk, kg);
        __builtin_amdgcn_s_setprio(1);
        #pragma unroll
        for (int q = 0; q < 3; ++q) {
            int f = (q < 2) ? (wv * 4 + hy * 2 + q) : (16 + wv * 2 + hy);
            bf16x8 b = *(const bf16x8*)(WT + OFF_U + (size_t)(f * 8 + kk) * 512 + lane * 8);
            if (q < 2) {
                aO[q][0] = __builtin_amdgcn_mfma_f32_16x16x32_bf16(a0, b, aO[q][0], 0, 0, 0);
                aO[q][1] = __builtin_amdgcn_mfma_f32_16x16x32_bf16(a1, b, aO[q][1], 0, 0, 0);
            } else {
                aG[0] = __builtin_amdgcn_mfma_f32_16x16x32_bf16(a0, b, aG[0], 0, 0, 0);
                aG[1] = __builtin_amdgcn_mfma_f32_16x16x32_bf16(a1, b, aG[1], 0, 0, 0);
            }
        }
        __builtin_amdgcn_s_setprio(0);
    }

    #pragma unroll
    for (int q = 0; q < 2; ++q)
        #pragma unroll
        for (int rg = 0; rg < 2; ++rg)
            #pragma unroll
            for (int j = 0; j < 4; ++j)
                aO[q][rg][j] *= s2v[rg][j];

    #pragma unroll
    for (int kk = 0; kk < 4; ++kk) {
        bf16x8 a0 = ldA(&xd[0][0], 128, cb, kk, kg);
        bf16x8 a1 = ldA(&xd[0][0], 128, 16 + cb, kk, kg);
        __builtin_amdgcn_s_setprio(1);
        #pragma unroll
        for (int q = 0; q < 2; ++q) {
            int f = wv * 4 + hy * 2 + q;
            bf16x8 b = *(const bf16x8*)(WT + OFF_D + (size_t)(f * 4 + kk) * 512 + lane * 8);
            aO[q][0] = __builtin_amdgcn_mfma_f32_16x16x32_bf16(a0, b, aO[q][0], 0, 0, 0);
            aO[q][1] = __builtin_amdgcn_mfma_f32_16x16x32_bf16(a1, b, aO[q][1], 0, 0, 0);
        }
        __builtin_amdgcn_s_setprio(0);
    }

    // out0 epilogue -> bf16 scratch
    #pragma unroll
    for (int q = 0; q < 2; ++q) {
        int col = wv * 64 + hy * 32 + q * 16 + cb;
        float bb = sBias[col];
        #pragma unroll
        for (int rg = 0; rg < 2; ++rg)
            #pragma unroll
            for (int j = 0; j < 4; ++j) {
                int row = rg * 16 + kg * 4 + j;
                scr[(size_t)(n0 + row) * DIMX + col] = f2bf(aO[q][rg][j] + bb);
            }
    }

    // ---- V phase ----
    f32x4 aV[2][3][2];
    #pragma unroll
    for (int q = 0; q < 2; ++q)
        #pragma unroll
        for (int j = 0; j < 3; ++j) { aV[q][j][0] = (f32x4){0,0,0,0}; aV[q][j][1] = (f32x4){0,0,0,0}; }

    #pragma unroll
    for (int kk = 0; kk < 4; ++kk) {
        bf16x8 av[3][2];
        #pragma unroll
        for (int j = 0; j < 3; ++j) {
            av[j][0] = ldA(&xv[j][0][0], 128, cb, kk, kg);
            av[j][1] = ldA(&xv[j][0][0], 128, 16 + cb, kk, kg);
        }
        __builtin_amdgcn_s_setprio(1);
        #pragma unroll
        for (int q = 0; q < 2; ++q) {
            int f = (q == 0) ? (wv * 2 + hy) : (8 + wv * 2 + hy);
            bf16x8 b = *(const bf16x8*)(WT + OFF_V + (size_t)(f * 4 + kk) * 512 + lane * 8);
            #pragma unroll
            for (int j = 0; j < 3; ++j) {
                aV[q][j][0] = __builtin_amdgcn_mfma_f32_16x16x32_bf16(av[j][0], b, aV[q][j][0], 0, 0, 0);
                aV[q][j][1] = __builtin_amdgcn_mfma_f32_16x16x32_bf16(av[j][1], b, aV[q][j][1], 0, 0, 0);
            }
        }
        __builtin_amdgcn_s_setprio(0);
    }

    // out1 epilogue -> bf16 scratch
    {
        int w = wv * 32 + hy * 16 + cb;
        #pragma unroll
        for (int rg = 0; rg < 2; ++rg)
            #pragma unroll
            for (int j = 0; j < 4; ++j) {
                int row = rg * 16 + kg * 4 + j;
                int n = n0 + row;
                float g   = aG[rg][j];
                float s2r = sY[row][0];
                float w2x = sY[row][1], w2y = sY[row][2], w2z = sY[row][3];
                float P0 = aV[0][0][rg][j], P1 = aV[0][1][rg][j], P2 = aV[0][2][rg][j];
                float Q0 = aV[1][0][rg][j], Q1 = aV[1][1][rg][j], Q2 = aV[1][2][rg][j];
                float e0 = w2x * g + s2r * P0 + w2z * Q1 - w2y * Q2;
                float e1 = w2y * g + s2r * P1 + w2x * Q2 - w2z * Q0;
                float e2 = w2z * g + s2r * P2 + w2y * Q0 - w2x * Q1;
                unsigned short* sp = scr + (size_t)n * DIMX + M0 + 3 * w;
                sp[0] = f2bf(e0); sp[1] = f2bf(e1); sp[2] = f2bf(e2);
            }
    }
}

// ---------------------------------------------------------------------------
// k2_norm: final configuration. 640 thr = 160 col x 4 row-lanes, fused
// stats+apply; reads bf16 scratch (ushort4), writes fp32 out.
// ---------------------------------------------------------------------------
__global__ __launch_bounds__(640)
void k2_norm(float* __restrict__ out, const unsigned short* __restrict__ scr,
             const int* __restrict__ batch,
             const float* __restrict__ mean_shift, const float* __restrict__ aw,
             const float* __restrict__ ab)
{
    __shared__ float sS[4][DIMX];
    __shared__ float sQ[4][DIMX];
    __shared__ float sScale[DIMX];
    __shared__ float sShift[DIMX];
    __shared__ int   sSE[2];

    const int g = blockIdx.x;
    const int t = threadIdx.x;
    if (t == 0) {
        sSE[0] = lower_bound_i(batch, N_ROWS, g);
        sSE[1] = lower_bound_i(batch, N_ROWS, g + 1);
    }
    __syncthreads();
    const int start = sSE[0], end = sSE[1];
    float cnt = (float)(end - start);
    if (cnt < 1.f) cnt = 1.f;

    const int rl = t / 160;     // row lane 0..3
    const int ct = t % 160;     // col thread
    const int c0 = ct * 4;

    // pass 1: accumulate from bf16 scratch
    float4 s4 = make_float4(0.f, 0.f, 0.f, 0.f);
    float4 q4 = make_float4(0.f, 0.f, 0.f, 0.f);
    for (int n = start + rl; n < end; n += 4) {
        ushort4 u = *(const ushort4*)(scr + (size_t)n * DIMX + c0);
        float4 v = make_float4(bf2f(u.x), bf2f(u.y), bf2f(u.z), bf2f(u.w));
        s4.x += v.x; q4.x = fmaf(v.x, v.x, q4.x);
        s4.y += v.y; q4.y = fmaf(v.y, v.y, q4.y);
        s4.z += v.z; q4.z = fmaf(v.z, v.z, q4.z);
        s4.w += v.w; q4.w = fmaf(v.w, v.w, q4.w);
    }
    *(float4*)&sS[rl][c0] = s4;
    *(float4*)&sQ[rl][c0] = q4;
    __syncthreads();

    // per-column totals (thread t owns column t)
    float sum = sS[0][t] + sS[1][t] + sS[2][t] + sS[3][t];
    float sq  = sQ[0][t] + sQ[1][t] + sQ[2][t] + sQ[3][t];

    if (t < M0) {
        float mean = sum / cnt;
        float esq  = sq / cnt;
        float ms   = mean_shift[t];
        float var  = esq - 2.f * ms * mean * mean + ms * ms * mean * mean;
        float sc   = rsqrtf(var + EPSV) * aw[t];
        sScale[t] = sc;
        sShift[t] = ab[t] - mean * ms * sc;
    } else {
        sQ[0][t] = sq;
    }
    __syncthreads();
    if (t >= M0) {
        int w = (t - M0) / 3;
        float qq = sQ[0][M0 + 3 * w] + sQ[0][M0 + 3 * w + 1] + sQ[0][M0 + 3 * w + 2];
        sScale[t] = rsqrtf(qq / (3.f * cnt) + EPSV) * aw[M0 + w];
        sShift[t] = 0.f;
    }
    __syncthreads();

    // pass 2: apply (read scratch again — L3-warm), write fp32 out
    const float4 sc4 = *(const float4*)&sScale[c0];
    const float4 sh4 = *(const float4*)&sShift[c0];
    for (int n = start + rl; n < end; n += 4) {
        ushort4 u = *(const ushort4*)(scr + (size_t)n * DIMX + c0);
        float4 v = make_float4(bf2f(u.x), bf2f(u.y), bf2f(u.z), bf2f(u.w));
        v.x = fmaf(v.x, sc4.x, sh4.x);
        v.y = fmaf(v.y, sc4.y, sh4.y);
        v.z = fmaf(v.z, sc4.z, sh4.z);
        v.w = fmaf(v.w, sc4.w, sh4.w);
        *(float4*)(out + (size_t)n * DIMX + c0) = v;
    }
}

// ---------------------------------------------------------------------------
extern "C" void kernel_launch(void* const* d_in, const int* in_sizes, int n_in,
                              void* d_out, int out_size, void* d_ws, size_t ws_size,
                              hipStream_t stream)
{
    const float* x     = (const float*)d_in[0];
    const float* y     = (const float*)d_in[1];
    const float* w000  = (const float*)d_in[2];
    const float* w011  = (const float*)d_in[3];
    const float* w101  = (const float*)d_in[4];
    const float* w110  = (const float*)d_in[5];
    const float* w111  = (const float*)d_in[6];
    const float* bias0 = (const float*)d_in[7];
    const float* mshift= (const float*)d_in[8];
    const float* aw    = (const float*)d_in[9];
    const float* ab    = (const float*)d_in[10];
    const int*   batch = (const int*)d_in[11];
    float* out = (float*)d_out;

    unsigned short* WT  = (unsigned short*)d_ws;
    unsigned short* scr = WT + WT_TOTAL;   // 100000*640 bf16 = 128 MB

    k0_pack<<<WT_TOTAL / 256, 256, 0, stream>>>(w000, w011, w101, w110, w111, WT);
    k1_mfma<<<(N_ROWS / BM) * 2, 256, 0, stream>>>(x, y, WT, bias0, scr);
    k2_norm<<<NG, 640, 0, stream>>>(out, scr, batch, mshift, aw, ab);
}

// Round 20
// 288.133 us; speedup vs baseline: 1.2685x; 1.0636x over previous
//
#include <hip/hip_runtime.h>
#include <math.h>

#define N_ROWS 100000
#define NG     2000
#define M0     256
#define M1     128
#define DIMX   640
#define EPSV   1e-5f
#define BM     32

#define INV_SQRT3 0.57735026918962576f
#define INV_SQRT2 0.70710678118654752f

#define OFF_U  0
#define OFF_D  98304
#define OFF_V  131072
#define WT_TOTAL 163840

#define N_TILES 3125           // N_ROWS / BM
#define TPX     391            // ceil(3125/8): tiles per XCD chunk
#define GRID_K1 6256           // 8 XCDs * 782 (= 2*391) blocks

typedef __attribute__((ext_vector_type(8))) short bf16x8;
typedef __attribute__((ext_vector_type(4))) float f32x4;

__device__ __forceinline__ unsigned short f2bf(float f) {
    union { float f; unsigned int u; } v; v.f = f;
    unsigned int r = v.u + 0x7fff + ((v.u >> 16) & 1);
    return (unsigned short)(r >> 16);
}
__device__ __forceinline__ float bf2f(unsigned short u) {
    union { unsigned int u; float f; } v; v.u = ((unsigned int)u) << 16; return v.f;
}

__device__ __forceinline__ int lower_bound_i(const int* __restrict__ b, int n, int key) {
    int lo = 0, hi = n;
    while (lo < hi) { int m = (lo + hi) >> 1; if (b[m] < key) lo = m + 1; else hi = m; }
    return lo;
}

// ---------------------------------------------------------------------------
// k0: pack weights -> bf16 per-MFMA-tile layout, scales folded. (frozen)
// ---------------------------------------------------------------------------
__global__ __launch_bounds__(256)
void k0_pack(const float* __restrict__ w000, const float* __restrict__ w011,
             const float* __restrict__ w101, const float* __restrict__ w110,
             const float* __restrict__ w111, unsigned short* __restrict__ WT)
{
    int i = blockIdx.x * 256 + threadIdx.x;
    if (i >= WT_TOTAL) return;
    int l = (i >> 3) & 63, e = i & 7;
    int lc = l & 15, lk = (l >> 4) << 3;
    float val;
    if (i < OFF_D) {
        int tile = i >> 9; int f = tile >> 3, kk = tile & 7;
        int col = f * 16 + lc, k = kk * 32 + lk + e;
        val = (col < 256) ? w000[k * 256 + col] : w011[k * 128 + (col - 256)];
    } else if (i < OFF_V) {
        int j = i - OFF_D; int tile = j >> 9; int f = tile >> 2, kk = tile & 3;
        int col = f * 16 + lc, k = kk * 32 + lk + e;
        val = w110[k * 256 + col] * INV_SQRT3;
    } else {
        int j = i - OFF_V; int tile = j >> 9; int f = tile >> 2, kk = tile & 3;
        int col = f * 16 + lc, k = kk * 32 + lk + e;
        val = (col < 128) ? w101[k * 128 + col]
                          : w111[k * 128 + (col - 128)] * INV_SQRT2;
    }
    WT[i] = f2bf(val);
}

__device__ __forceinline__ bf16x8 ldA(const unsigned short* base, int KW,
                                      int row, int kk, int kg)
{
    int off = row * KW + (((kk << 5) + (kg << 3)) ^ ((row & 7) << 3));
    return *(const bf16x8*)(base + off);
}

// ---------------------------------------------------------------------------
// k1: R18 body frozen; ONE delta: XCD co-location of hy-pairs.
// blockIdx B -> xcd = B&7, j = B>>3, tile t = xcd*391 + (j>>1), hy = j&1.
// Both hy-blocks of a tile land on the same XCD (same w%8 class), so the
// second one's x-staging hits that XCD's L2. Guard t < 3125 (uniform exit).
// ---------------------------------------------------------------------------
__global__ __launch_bounds__(256, 3)
void k1_mfma(const float* __restrict__ x, const float* __restrict__ y,
             const unsigned short* __restrict__ WT, const float* __restrict__ bias0,
             unsigned short* __restrict__ scr)
{
    __shared__ unsigned short xs1[BM][256];
    __shared__ unsigned short xv[3][BM][128];
    __shared__ unsigned short xd[BM][128];
    __shared__ float sY[BM][4];
    __shared__ float sBias[256];

    const int B    = blockIdx.x;
    const int xcd  = B & 7;
    const int jj   = B >> 3;
    const int tile = xcd * TPX + (jj >> 1);
    if (tile >= N_TILES) return;           // whole-block uniform, pre-barrier
    const int hy   = jj & 1;
    const int n0   = tile * BM;

    const int t    = threadIdx.x;
    const int lane = t & 63;
    const int wv   = t >> 6;
    const int cb   = lane & 15;
    const int kg   = lane >> 4;

    if (t < 128) sY[t >> 2][t & 3] = y[(size_t)(n0 + (t >> 2)) * 4 + (t & 3)];
    sBias[t] = bias0[t];

    // ---- stage x once: s1 and deinterleaved v1 ----
    #pragma unroll
    for (int i = 0; i < 8; ++i) {
        int idx = i * 256 + t;
        int r = idx >> 6, c4 = idx & 63;
        float4 v = *(const float4*)(x + (size_t)(n0 + r) * DIMX + c4 * 4);
        ushort4 o = { f2bf(v.x), f2bf(v.y), f2bf(v.z), f2bf(v.w) };
        *(ushort4*)&xs1[r][(c4 * 4) ^ ((r & 7) << 3)] = o;
    }
    #pragma unroll
    for (int i = 0; i < 4; ++i) {
        int idx = i * 256 + t;
        int r = idx >> 5, q = idx & 31;
        const float* vp = x + (size_t)(n0 + r) * DIMX + M0 + q * 12;
        float4 a = *(const float4*)vp;
        float4 b = *(const float4*)(vp + 4);
        float4 c = *(const float4*)(vp + 8);
        int off = (q * 4) ^ ((r & 7) << 3);
        ushort4 ox = { f2bf(a.x), f2bf(a.w), f2bf(b.z), f2bf(c.y) };
        ushort4 oy = { f2bf(a.y), f2bf(b.x), f2bf(b.w), f2bf(c.z) };
        ushort4 oz = { f2bf(a.z), f2bf(b.y), f2bf(c.x), f2bf(c.w) };
        *(ushort4*)&xv[0][r][off] = ox;
        *(ushort4*)&xv[1][r][off] = oy;
        *(ushort4*)&xv[2][r][off] = oz;
    }
    __syncthreads();

    // ---- d = v1 . v2 ----
    #pragma unroll
    for (int i = 0; i < 4; ++i) {
        int idx = i * 256 + t;
        int r = idx >> 5, q = idx & 31;
        int off = (q * 4) ^ ((r & 7) << 3);
        ushort4 ux = *(const ushort4*)&xv[0][r][off];
        ushort4 uy = *(const ushort4*)&xv[1][r][off];
        ushort4 uz = *(const ushort4*)&xv[2][r][off];
        float v2x = sY[r][1], v2y = sY[r][2], v2z = sY[r][3];
        ushort4 od;
        od.x = f2bf(bf2f(ux.x) * v2x + bf2f(uy.x) * v2y + bf2f(uz.x) * v2z);
        od.y = f2bf(bf2f(ux.y) * v2x + bf2f(uy.y) * v2y + bf2f(uz.y) * v2z);
        od.z = f2bf(bf2f(ux.z) * v2x + bf2f(uy.z) * v2y + bf2f(uz.z) * v2z);
        od.w = f2bf(bf2f(ux.w) * v2x + bf2f(uy.w) * v2y + bf2f(uz.w) * v2z);
        *(ushort4*)&xd[r][off] = od;
    }
    __syncthreads();

    float s2v[2][4];
    #pragma unroll
    for (int rg = 0; rg < 2; ++rg)
        #pragma unroll
        for (int j = 0; j < 4; ++j)
            s2v[rg][j] = sY[rg * 16 + kg * 4 + j][0];

    // ---- U phase: [out0_raw | G2] = s1 @ [W000 | W011], K=256 ----
    f32x4 aO[2][2];
    f32x4 aG[2];
    #pragma unroll
    for (int q = 0; q < 2; ++q) { aO[q][0] = (f32x4){0,0,0,0}; aO[q][1] = (f32x4){0,0,0,0}; }
    aG[0] = (f32x4){0,0,0,0}; aG[1] = (f32x4){0,0,0,0};

    #pragma unroll
    for (int kk = 0; kk < 8; ++kk) {
        bf16x8 a0 = ldA(&xs1[0][0], 256, cb, kk, kg);
        bf16x8 a1 = ldA(&xs1[0][0], 256, 16 + cb, kk, kg);
        __builtin_amdgcn_s_setprio(1);
        #pragma unroll
        for (int q = 0; q < 3; ++q) {
            int f = (q < 2) ? (wv * 4 + hy * 2 + q) : (16 + wv * 2 + hy);
            bf16x8 b = *(const bf16x8*)(WT + OFF_U + (size_t)(f * 8 + kk) * 512 + lane * 8);
            if (q < 2) {
                aO[q][0] = __builtin_amdgcn_mfma_f32_16x16x32_bf16(a0, b, aO[q][0], 0, 0, 0);
                aO[q][1] = __builtin_amdgcn_mfma_f32_16x16x32_bf16(a1, b, aO[q][1], 0, 0, 0);
            } else {
                aG[0] = __builtin_amdgcn_mfma_f32_16x16x32_bf16(a0, b, aG[0], 0, 0, 0);
                aG[1] = __builtin_amdgcn_mfma_f32_16x16x32_bf16(a1, b, aG[1], 0, 0, 0);
            }
        }
        __builtin_amdgcn_s_setprio(0);
    }

    #pragma unroll
    for (int q = 0; q < 2; ++q)
        #pragma unroll
        for (int rg = 0; rg < 2; ++rg)
            #pragma unroll
            for (int j = 0; j < 4; ++j)
                aO[q][rg][j] *= s2v[rg][j];

    #pragma unroll
    for (int kk = 0; kk < 4; ++kk) {
        bf16x8 a0 = ldA(&xd[0][0], 128, cb, kk, kg);
        bf16x8 a1 = ldA(&xd[0][0], 128, 16 + cb, kk, kg);
        __builtin_amdgcn_s_setprio(1);
        #pragma unroll
        for (int q = 0; q < 2; ++q) {
            int f = wv * 4 + hy * 2 + q;
            bf16x8 b = *(const bf16x8*)(WT + OFF_D + (size_t)(f * 4 + kk) * 512 + lane * 8);
            aO[q][0] = __builtin_amdgcn_mfma_f32_16x16x32_bf16(a0, b, aO[q][0], 0, 0, 0);
            aO[q][1] = __builtin_amdgcn_mfma_f32_16x16x32_bf16(a1, b, aO[q][1], 0, 0, 0);
        }
        __builtin_amdgcn_s_setprio(0);
    }

    // out0 epilogue -> bf16 scratch
    #pragma unroll
    for (int q = 0; q < 2; ++q) {
        int col = wv * 64 + hy * 32 + q * 16 + cb;
        float bb = sBias[col];
        #pragma unroll
        for (int rg = 0; rg < 2; ++rg)
            #pragma unroll
            for (int j = 0; j < 4; ++j) {
                int row = rg * 16 + kg * 4 + j;
                scr[(size_t)(n0 + row) * DIMX + col] = f2bf(aO[q][rg][j] + bb);
            }
    }

    // ---- V phase ----
    f32x4 aV[2][3][2];
    #pragma unroll
    for (int q = 0; q < 2; ++q)
        #pragma unroll
        for (int j = 0; j < 3; ++j) { aV[q][j][0] = (f32x4){0,0,0,0}; aV[q][j][1] = (f32x4){0,0,0,0}; }

    #pragma unroll
    for (int kk = 0; kk < 4; ++kk) {
        bf16x8 av[3][2];
        #pragma unroll
        for (int j = 0; j < 3; ++j) {
            av[j][0] = ldA(&xv[j][0][0], 128, cb, kk, kg);
            av[j][1] = ldA(&xv[j][0][0], 128, 16 + cb, kk, kg);
        }
        __builtin_amdgcn_s_setprio(1);
        #pragma unroll
        for (int q = 0; q < 2; ++q) {
            int f = (q == 0) ? (wv * 2 + hy) : (8 + wv * 2 + hy);
            bf16x8 b = *(const bf16x8*)(WT + OFF_V + (size_t)(f * 4 + kk) * 512 + lane * 8);
            #pragma unroll
            for (int j = 0; j < 3; ++j) {
                aV[q][j][0] = __builtin_amdgcn_mfma_f32_16x16x32_bf16(av[j][0], b, aV[q][j][0], 0, 0, 0);
                aV[q][j][1] = __builtin_amdgcn_mfma_f32_16x16x32_bf16(av[j][1], b, aV[q][j][1], 0, 0, 0);
            }
        }
        __builtin_amdgcn_s_setprio(0);
    }

    // out1 epilogue -> bf16 scratch
    {
        int w = wv * 32 + hy * 16 + cb;
        #pragma unroll
        for (int rg = 0; rg < 2; ++rg)
            #pragma unroll
            for (int j = 0; j < 4; ++j) {
                int row = rg * 16 + kg * 4 + j;
                int n = n0 + row;
                float g   = aG[rg][j];
                float s2r = sY[row][0];
                float w2x = sY[row][1], w2y = sY[row][2], w2z = sY[row][3];
                float P0 = aV[0][0][rg][j], P1 = aV[0][1][rg][j], P2 = aV[0][2][rg][j];
                float Q0 = aV[1][0][rg][j], Q1 = aV[1][1][rg][j], Q2 = aV[1][2][rg][j];
                float e0 = w2x * g + s2r * P0 + w2z * Q1 - w2y * Q2;
                float e1 = w2y * g + s2r * P1 + w2x * Q2 - w2z * Q0;
                float e2 = w2z * g + s2r * P2 + w2y * Q0 - w2x * Q1;
                unsigned short* sp = scr + (size_t)n * DIMX + M0 + 3 * w;
                sp[0] = f2bf(e0); sp[1] = f2bf(e1); sp[2] = f2bf(e2);
            }
    }
}

// ---------------------------------------------------------------------------
// k2_norm: frozen final configuration. 640 thr = 160 col x 4 row-lanes,
// fused stats+apply; reads bf16 scratch (ushort4), writes fp32 out.
// ---------------------------------------------------------------------------
__global__ __launch_bounds__(640)
void k2_norm(float* __restrict__ out, const unsigned short* __restrict__ scr,
             const int* __restrict__ batch,
             const float* __restrict__ mean_shift, const float* __restrict__ aw,
             const float* __restrict__ ab)
{
    __shared__ float sS[4][DIMX];
    __shared__ float sQ[4][DIMX];
    __shared__ float sScale[DIMX];
    __shared__ float sShift[DIMX];
    __shared__ int   sSE[2];

    const int g = blockIdx.x;
    const int t = threadIdx.x;
    if (t == 0) {
        sSE[0] = lower_bound_i(batch, N_ROWS, g);
        sSE[1] = lower_bound_i(batch, N_ROWS, g + 1);
    }
    __syncthreads();
    const int start = sSE[0], end = sSE[1];
    float cnt = (float)(end - start);
    if (cnt < 1.f) cnt = 1.f;

    const int rl = t / 160;     // row lane 0..3
    const int ct = t % 160;     // col thread
    const int c0 = ct * 4;

    // pass 1: accumulate from bf16 scratch
    float4 s4 = make_float4(0.f, 0.f, 0.f, 0.f);
    float4 q4 = make_float4(0.f, 0.f, 0.f, 0.f);
    for (int n = start + rl; n < end; n += 4) {
        ushort4 u = *(const ushort4*)(scr + (size_t)n * DIMX + c0);
        float4 v = make_float4(bf2f(u.x), bf2f(u.y), bf2f(u.z), bf2f(u.w));
        s4.x += v.x; q4.x = fmaf(v.x, v.x, q4.x);
        s4.y += v.y; q4.y = fmaf(v.y, v.y, q4.y);
        s4.z += v.z; q4.z = fmaf(v.z, v.z, q4.z);
        s4.w += v.w; q4.w = fmaf(v.w, v.w, q4.w);
    }
    *(float4*)&sS[rl][c0] = s4;
    *(float4*)&sQ[rl][c0] = q4;
    __syncthreads();

    // per-column totals (thread t owns column t)
    float sum = sS[0][t] + sS[1][t] + sS[2][t] + sS[3][t];
    float sq  = sQ[0][t] + sQ[1][t] + sQ[2][t] + sQ[3][t];

    if (t < M0) {
        float mean = sum / cnt;
        float esq  = sq / cnt;
        float ms   = mean_shift[t];
        float var  = esq - 2.f * ms * mean * mean + ms * ms * mean * mean;
        float sc   = rsqrtf(var + EPSV) * aw[t];
        sScale[t] = sc;
        sShift[t] = ab[t] - mean * ms * sc;
    } else {
        sQ[0][t] = sq;
    }
    __syncthreads();
    if (t >= M0) {
        int w = (t - M0) / 3;
        float qq = sQ[0][M0 + 3 * w] + sQ[0][M0 + 3 * w + 1] + sQ[0][M0 + 3 * w + 2];
        sScale[t] = rsqrtf(qq / (3.f * cnt) + EPSV) * aw[M0 + w];
        sShift[t] = 0.f;
    }
    __syncthreads();

    // pass 2: apply (read scratch again — L3-warm), write fp32 out
    const float4 sc4 = *(const float4*)&sScale[c0];
    const float4 sh4 = *(const float4*)&sShift[c0];
    for (int n = start + rl; n < end; n += 4) {
        ushort4 u = *(const ushort4*)(scr + (size_t)n * DIMX + c0);
        float4 v = make_float4(bf2f(u.x), bf2f(u.y), bf2f(u.z), bf2f(u.w));
        v.x = fmaf(v.x, sc4.x, sh4.x);
        v.y = fmaf(v.y, sc4.y, sh4.y);
        v.z = fmaf(v.z, sc4.z, sh4.z);
        v.w = fmaf(v.w, sc4.w, sh4.w);
        *(float4*)(out + (size_t)n * DIMX + c0) = v;
    }
}

// ---------------------------------------------------------------------------
extern "C" void kernel_launch(void* const* d_in, const int* in_sizes, int n_in,
                              void* d_out, int out_size, void* d_ws, size_t ws_size,
                              hipStream_t stream)
{
    const float* x     = (const float*)d_in[0];
    const float* y     = (const float*)d_in[1];
    const float* w000  = (const float*)d_in[2];
    const float* w011  = (const float*)d_in[3];
    const float* w101  = (const float*)d_in[4];
    const float* w110  = (const float*)d_in[5];
    const float* w111  = (const float*)d_in[6];
    const float* bias0 = (const float*)d_in[7];
    const float* mshift= (const float*)d_in[8];
    const float* aw    = (const float*)d_in[9];
    const float* ab    = (const float*)d_in[10];
    const int*   batch = (const int*)d_in[11];
    float* out = (float*)d_out;

    unsigned short* WT  = (unsigned short*)d_ws;
    unsigned short* scr = WT + WT_TOTAL;   // 100000*640 bf16 = 128 MB

    k0_pack<<<WT_TOTAL / 256, 256, 0, stream>>>(w000, w011, w101, w110, w111, WT);
    k1_mfma<<<GRID_K1, 256, 0, stream>>>(x, y, WT, bias0, scr);
    k2_norm<<<NG, 640, 0, stream>>>(out, scr, batch, mshift, aw, ab);
}